// Round 4
// baseline (566.942 us; speedup 1.0000x reference)
//
#include <hip/hip_runtime.h>
#include <hip/hip_bf16.h>
#include <stdint.h>

typedef unsigned short u16;
typedef unsigned int u32;
typedef __attribute__((ext_vector_type(8))) short short8;
typedef __attribute__((ext_vector_type(4))) float f32x4;
typedef __attribute__((ext_vector_type(4))) int i32x4;

static __device__ __forceinline__ u16 f2bf(float f) {
  union { __hip_bfloat16 b; u16 u; } c;
  c.b = __float2bfloat16(f);
  return c.u;
}
static __device__ __forceinline__ float bf2f(u16 u) {
  return __uint_as_float(((u32)u) << 16);
}

// ---------------- merged prep: x -> q1,q2 i8 (x ~= q1/16 + q2/4096); w -> sign i8 ----------------
// blocks [0, 32768): X path. blocks [32768, 49152): W path. Clean block-granular split.
__global__ __launch_bounds__(256) void prep_all(const float* __restrict__ X,
                                                const float* __restrict__ W,
                                                char* __restrict__ A1,
                                                char* __restrict__ A2,
                                                char* __restrict__ Qw) {
  const u32 t = blockIdx.x * 256 + threadIdx.x;
  const u32 NX = 8388608u;  // M*K/4 float4s
  if (t < NX) {
    const float4 v = ((const float4*)X)[t];
    const float vv[4] = {v.x, v.y, v.z, v.w};
    u32 p1 = 0, p2 = 0;
#pragma unroll
    for (int j = 0; j < 4; ++j) {
      float q1f = rintf(vv[j] * 16.f);
      q1f = fminf(fmaxf(q1f, -127.f), 127.f);
      const float r = vv[j] - q1f * 0.0625f;
      float q2f = rintf(r * 4096.f);
      q2f = fminf(fmaxf(q2f, -127.f), 127.f);
      p1 |= ((u32)((int)q1f & 0xFF)) << (8 * j);
      p2 |= ((u32)((int)q2f & 0xFF)) << (8 * j);
    }
    ((u32*)A1)[t] = p1;
    ((u32*)A2)[t] = p2;
  } else {
    const u32 tw = t - NX;
    const float4 v = ((const float4*)W)[tw];
    const float vv[4] = {v.x, v.y, v.z, v.w};
    u32 p = 0;
#pragma unroll
    for (int j = 0; j < 4; ++j) {
      const u32 b = __float_as_uint(vv[j]);
      const int q = ((b << 1) == 0) ? 0 : ((b >> 31) ? -1 : 1);
      p |= ((u32)(q & 0xFF)) << (8 * j);
    }
    ((u32*)Qw)[tw] = p;
  }
}

// ---------------- fused two-term i8 GEMM ----------------
// BM=256 BN=128 BK=64, 8 waves (4m x 2n), per-wave 64x64, both terms in one pass.
// LDS per parity (40960 B): A1[0,16K) A2[16K,32K) B[32K,40K); double-buffered = 80 KB.
// Row-pair layout: two 64-B K-rows per 128-B line; 16B-slot ^= (line&7) -> conflict-free.
#define LGKM0 asm volatile("s_waitcnt lgkmcnt(0)" ::: "memory")
#define VMCNT(n) asm volatile("s_waitcnt vmcnt(" #n ")" ::: "memory")
#define CFENCE asm volatile("" ::: "memory")
#define BAR do { __builtin_amdgcn_s_barrier(); CFENCE; } while (0)

static __device__ __forceinline__ void gload16(const void* g, void* l) {
  __builtin_amdgcn_global_load_lds(
      (const __attribute__((address_space(1))) u32*)g,
      (__attribute__((address_space(3))) u32*)l, 16, 0, 0);
}

__global__ __launch_bounds__(512, 2)
void gemm_fused_i8(const char* __restrict__ A1, const char* __restrict__ A2,
                   const char* __restrict__ B, const float* __restrict__ Bias,
                   float* __restrict__ C) {
  __shared__ __align__(16) unsigned char ldsc[81920];
  char* const lc = (char*)ldsc;

  const int tid = threadIdx.x;
  const int lane = tid & 63;
  const int wid = tid >> 6;
  const int wm = wid >> 1;      // 0..3 (64-row slab)
  const int wn = wid & 1;       // 0..1 (64-col slab)
  const int r16 = lane & 15;
  const int kq = lane >> 4;     // 0..3 (16-byte K-chunk)

  // XCD-bijective swizzle (1024 blocks, %8==0)
  const int bid = blockIdx.x;
  const int swz = (bid & 7) * 128 + (bid >> 3);
  const int brow = swz >> 5;    // 0..31
  const int bcol = swz & 31;    // 0..31

  // ---- staging: linear LDS dest (tid*16) + inverse-swizzled global source ----
  // op covers 128 rows x 64 B: thread t -> line srp=t>>3, slot t&7; unswizzled
  // slot sc = (t&7)^(srp&7) -> source row = srp*2 + (sc>>2), col byte (sc&3)*16.
  const int srp = tid >> 3;
  const int sc = (tid & 7) ^ (srp & 7);
  const u32 srcoff = (u32)(srp * 2 + (sc >> 2)) * 4096u + (u32)((sc & 3) * 16);
  const char* Ag1 = A1 + (size_t)(brow * 256) * 4096 + srcoff;
  const char* Ag2 = A2 + (size_t)(brow * 256) * 4096 + srcoff;
  const char* Bgp = B + (size_t)(bcol * 128) * 4096 + srcoff;
  const u32 l_t = (u32)tid * 16u;

  // ---- ds-read addressing ----
  // element (row, kq) at: (row>>1)*128 + ((((row&1)*4 + kq) ^ ((row>>1)&7)) * 16)
  // within a frag: row = wm*64 + mf*16 + r16 -> line&7 = r16>>1 (mf*8, wm*32 are %8==0)
  const u32 slot = (u32)(((((r16 & 1) * 4) + kq) ^ (r16 >> 1)) * 16);
  const u32 aBase = (u32)(wm * 4096 + (r16 >> 1) * 128) + slot;
  const u32 bBase = 32768u + (u32)(wn * 4096 + (r16 >> 1) * 128) + slot;

  i32x4 acc1[4][4], acc2[4][4];
#pragma unroll
  for (int m = 0; m < 4; ++m)
#pragma unroll
    for (int n = 0; n < 4; ++n)
#pragma unroll
      for (int j = 0; j < 4; ++j) { acc1[m][n][j] = 0; acc2[m][n][j] = 0; }
  i32x4 bq[4];

#define RD(off) (*(const i32x4*)(lc + (off)))
#define ARD(P, TERM, MF) RD((u32)((P)*40960 + (TERM)*16384 + (MF)*1024) + aBase)
#define BRD(P, NF) RD((u32)((P)*40960 + (NF)*1024) + bBase)

#define ST_A1(T, H, P) gload16(Ag1 + (size_t)(H)*128*4096 + (u32)(T)*64, \
                               lc + (u32)((P)*40960 + (H)*8192) + l_t)
#define ST_A2(T, H, P) gload16(Ag2 + (size_t)(H)*128*4096 + (u32)(T)*64, \
                               lc + (u32)((P)*40960 + 16384 + (H)*8192) + l_t)
#define ST_B(T, P) gload16(Bgp + (u32)(T)*64, lc + (u32)((P)*40960 + 32768) + l_t)

#define MFMA16(ACC, A0v, A1v, A2v, A3v) do { \
    _Pragma("unroll") for (int nf_ = 0; nf_ < 4; ++nf_) { \
      ACC[0][nf_] = __builtin_amdgcn_mfma_i32_16x16x64_i8(A0v, bq[nf_], ACC[0][nf_], 0, 0, 0); \
      ACC[1][nf_] = __builtin_amdgcn_mfma_i32_16x16x64_i8(A1v, bq[nf_], ACC[1][nf_], 0, 0, 0); \
      ACC[2][nf_] = __builtin_amdgcn_mfma_i32_16x16x64_i8(A2v, bq[nf_], ACC[2][nf_], 0, 0, 0); \
      ACC[3][nf_] = __builtin_amdgcn_mfma_i32_16x16x64_i8(A3v, bq[nf_], ACC[3][nf_], 0, 0, 0); \
    } } while (0)

  // PH0 of tile T (parity P): stage A2(T+1) into P^1; consume term 1.
#define PH0(P, S) do { \
    S; \
    const i32x4 a0 = ARD(P, 0, 0), a1v = ARD(P, 0, 1); \
    const i32x4 a2v = ARD(P, 0, 2), a3v = ARD(P, 0, 3); \
    bq[0] = BRD(P, 0); bq[1] = BRD(P, 1); bq[2] = BRD(P, 2); bq[3] = BRD(P, 3); \
    BAR; LGKM0; __builtin_amdgcn_sched_barrier(0); \
    __builtin_amdgcn_s_setprio(1); MFMA16(acc1, a0, a1v, a2v, a3v); \
    __builtin_amdgcn_s_setprio(0); BAR; } while (0)

  // PH1 of tile T (parity P): stage B/A1(T+2) into P; consume term 2; counted vmcnt.
#define PH1(P, S, TW) do { \
    S; \
    const i32x4 a0 = ARD(P, 1, 0), a1v = ARD(P, 1, 1); \
    const i32x4 a2v = ARD(P, 1, 2), a3v = ARD(P, 1, 3); \
    BAR; LGKM0; __builtin_amdgcn_sched_barrier(0); \
    __builtin_amdgcn_s_setprio(1); MFMA16(acc2, a0, a1v, a2v, a3v); \
    __builtin_amdgcn_s_setprio(0); TW; BAR; } while (0)

  // prologue: tile0 full (5 ops), tile1 A1+B (3 ops); keep tile1's 3 in flight
  ST_A1(0, 0, 0); ST_A1(0, 1, 0); ST_A2(0, 0, 0); ST_A2(0, 1, 0); ST_B(0, 0);
  ST_A1(1, 0, 1); ST_A1(1, 1, 1); ST_B(1, 1);
  VMCNT(3); BAR;

  int T = 0;
#pragma unroll 1
  for (int it = 0; it < 31; ++it) {  // tiles 0..61
    PH0(0, { ST_A2(T + 1, 0, 1); ST_A2(T + 1, 1, 1); });
    PH1(0, { ST_B(T + 2, 0); ST_A1(T + 2, 0, 0); ST_A1(T + 2, 1, 0); }, VMCNT(3));
    PH0(1, { ST_A2(T + 2, 0, 0); ST_A2(T + 2, 1, 0); });
    PH1(1, { ST_B(T + 3, 1); ST_A1(T + 3, 0, 1); ST_A1(T + 3, 1, 1); }, VMCNT(3));
    T += 2;
  }
  // tail: tiles 62, 63
  PH0(0, { ST_A2(63, 0, 1); ST_A2(63, 1, 1); });
  PH1(0, , VMCNT(0));
  PH0(1, );
  PH1(1, , );

  // ---- epilogue: C = acc1/16 + acc2/4096 + bias ----
  // C/D layout: col = lane&15, row = kq*4 + j
  const int ccol0 = bcol * 128 + wn * 64 + r16;
  float bb[4];
#pragma unroll
  for (int nf = 0; nf < 4; ++nf) bb[nf] = Bias[ccol0 + nf * 16];
  const int crow0 = brow * 256 + wm * 64 + kq * 4;
#pragma unroll
  for (int mf = 0; mf < 4; ++mf) {
    const int row = crow0 + mf * 16;
#pragma unroll
    for (int nf = 0; nf < 4; ++nf) {
      const int col = ccol0 + nf * 16;
#pragma unroll
      for (int j = 0; j < 4; ++j) {
        C[(size_t)(row + j) * 4096 + col] =
            (float)acc1[mf][nf][j] * 0.0625f +
            (float)acc2[mf][nf][j] * (1.0f / 4096.0f) + bb[nf];
      }
    }
  }
#undef RD
#undef ARD
#undef BRD
#undef ST_A1
#undef ST_A2
#undef ST_B
#undef MFMA16
#undef PH0
#undef PH1
}

// ---------------- fallback (round-1 kernel, any shape) ----------------
#define BM 128
#define BN 128
#define BKF 32
#define LDKP 40

__global__ __launch_bounds__(256, 2)
void bitnet_gemm_fallback(const float* __restrict__ X, const float* __restrict__ W,
                          const float* __restrict__ Bias, float* __restrict__ C,
                          int M, int N, int K) {
  __shared__ u16 AsH[BM][LDKP];
  __shared__ u16 AsL[BM][LDKP];
  __shared__ u16 Bs[BN][LDKP];
  const int nwg = gridDim.x;
  const int bid = blockIdx.x;
  const int swz = ((nwg & 7) == 0) ? ((bid & 7) * (nwg >> 3) + (bid >> 3)) : bid;
  const int nbn = N / BN;
  const int brow = swz / nbn;
  const int bcol = swz % nbn;
  const int tid = threadIdx.x;
  const int lane = tid & 63;
  const int wid = tid >> 6;
  const int wr = wid >> 1;
  const int wc = wid & 1;
  const int srow = tid >> 2;
  const int skc = (tid & 3) * 8;
  const float* Ab = X + (size_t)brow * BM * K;
  const float* Bb = W + (size_t)bcol * BN * K;
  f32x4 acc[4][4];
#pragma unroll
  for (int m = 0; m < 4; ++m)
#pragma unroll
    for (int n = 0; n < 4; ++n)
#pragma unroll
      for (int j = 0; j < 4; ++j) acc[m][n][j] = 0.f;
  const int r0 = lane & 15;
  const int k0 = (lane >> 4) * 8;
  for (int kt = 0; kt < K; kt += BKF) {
    __syncthreads();
#pragma unroll
    for (int p = 0; p < 2; ++p) {
      const int row = p * 64 + srow;
      const float* src = Ab + (size_t)row * K + kt + skc;
      const float4 v0 = *(const float4*)(src);
      const float4 v1 = *(const float4*)(src + 4);
      const float v[8] = {v0.x, v0.y, v0.z, v0.w, v1.x, v1.y, v1.z, v1.w};
      short8 ph, pl;
#pragma unroll
      for (int j = 0; j < 8; ++j) {
        const u16 h = f2bf(v[j]);
        const float rem = v[j] - bf2f(h);
        ph[j] = (short)h;
        pl[j] = (short)f2bf(rem);
      }
      *(short8*)&AsH[row][skc] = ph;
      *(short8*)&AsL[row][skc] = pl;
    }
#pragma unroll
    for (int p = 0; p < 2; ++p) {
      const int row = p * 64 + srow;
      const float* src = Bb + (size_t)row * K + kt + skc;
      const float4 v0 = *(const float4*)(src);
      const float4 v1 = *(const float4*)(src + 4);
      const float v[8] = {v0.x, v0.y, v0.z, v0.w, v1.x, v1.y, v1.z, v1.w};
      short8 pq;
#pragma unroll
      for (int j = 0; j < 8; ++j) {
        const u32 b = __float_as_uint(v[j]);
        const u16 q = ((b << 1) == 0) ? (u16)0 : (u16)(0x3F80u | ((b >> 16) & 0x8000u));
        pq[j] = (short)q;
      }
      *(short8*)&Bs[row][skc] = pq;
    }
    __syncthreads();
    short8 ah[4], al[4], bqf[4];
#pragma unroll
    for (int m = 0; m < 4; ++m) {
      ah[m] = *(const short8*)&AsH[wr * 64 + m * 16 + r0][k0];
      al[m] = *(const short8*)&AsL[wr * 64 + m * 16 + r0][k0];
    }
#pragma unroll
    for (int n = 0; n < 4; ++n)
      bqf[n] = *(const short8*)&Bs[wc * 64 + n * 16 + r0][k0];
#pragma unroll
    for (int m = 0; m < 4; ++m)
#pragma unroll
      for (int n = 0; n < 4; ++n) {
        acc[m][n] = __builtin_amdgcn_mfma_f32_16x16x32_bf16(ah[m], bqf[n], acc[m][n], 0, 0, 0);
        acc[m][n] = __builtin_amdgcn_mfma_f32_16x16x32_bf16(al[m], bqf[n], acc[m][n], 0, 0, 0);
      }
  }
  const int rbase = (lane >> 4) * 4;
  const int crow0 = brow * BM + wr * 64;
  const int ccol0 = bcol * BN + wc * 64;
#pragma unroll
  for (int n = 0; n < 4; ++n) {
    const int col = ccol0 + n * 16 + r0;
    const float bbv = Bias[col];
#pragma unroll
    for (int m = 0; m < 4; ++m) {
      const int row = crow0 + m * 16 + rbase;
#pragma unroll
      for (int j = 0; j < 4; ++j) {
        C[(size_t)(row + j) * N + col] = acc[m][n][j] + bbv;
      }
    }
  }
}

extern "C" void kernel_launch(void* const* d_in, const int* in_sizes, int n_in,
                              void* d_out, int out_size, void* d_ws, size_t ws_size,
                              hipStream_t stream) {
  const float* X = (const float*)d_in[0];     // [M, K] fp32
  const float* W = (const float*)d_in[1];     // [N, K] fp32
  const float* Bias = (const float*)d_in[2];  // [N] fp32
  float* C = (float*)d_out;                   // [M, N] fp32

  const int N = in_sizes[2];
  const int K = in_sizes[1] / N;
  const int M = in_sizes[0] / K;

  const size_t a_bytes = (size_t)M * K;  // i8 per term
  const size_t qw_bytes = (size_t)N * K;

  if (M == 8192 && N == 4096 && K == 4096 && ws_size >= 2 * a_bytes + qw_bytes) {
    char* A1 = (char*)d_ws;
    char* A2 = A1 + a_bytes;
    char* Qw = A2 + a_bytes;
    const int prep_grid = (int)((a_bytes + qw_bytes) / 4 / 256);  // 49152
    prep_all<<<prep_grid, 256, 0, stream>>>(X, W, A1, A2, Qw);
    const int grid = (M / 256) * (N / 128);  // 1024
    gemm_fused_i8<<<grid, 512, 0, stream>>>(A1, A2, Qw, Bias, C);
  } else {
    bitnet_gemm_fallback<<<(M / BM) * (N / BN), 256, 0, stream>>>(X, W, Bias, C, M, N, K);
  }
}